// Round 5
// baseline (93.887 us; speedup 1.0000x reference)
//
#include <hip/hip_runtime.h>

#define NB 16
#define BATCH 8
#define PLANE (512*512)           // 262144 px per channel plane
#define FBINS 512                 // fine histogram resolution
#define CHUNKS 128
#define THREADS 256
#define PX_PER_BLOCK (PLANE / CHUNKS)          // 2048
#define GROUPS (PX_PER_BLOCK / (THREADS * 4))  // 2 float4 iters
#define NOUT 96                                // 6 ch * 16 bins per (block,b)

#if __has_builtin(__builtin_amdgcn_exp2f)
__device__ __forceinline__ float exp2_fast(float x) { return __builtin_amdgcn_exp2f(x); }
#else
__device__ __forceinline__ float exp2_fast(float x) { return __expf(x * 0.69314718056f); }
#endif

// weight = exp(-128*(x - i/15)^2) = exp2( -(128*log2(e)/225) * (15x - i)^2 )
#define NEG_C2 (-0.8207331788f)

__device__ __forceinline__ int qbin(float x) {
    int f = (int)(x * (float)FBINS);
    return f > (FBINS - 1) ? (FBINS - 1) : f;
}

// ---------------------------------------------------------------------------
// 1) masked fine histogram + in-block Gaussian convolution.
//    LDS: cnt[3*FBINS] u32 packing two channels per word (lo16 = ch 2k,
//    hi16 = ch 2k+1; max half-count 2048 -> no carry), wtab[FBINS*NB] fp32.
//    Epilogue convolves cnt with wtab -> 96 floats -> partial[b][chunk][96].
//    Channel order h in [0,6): p0,p1,p2,t0,t1,t2.
// ---------------------------------------------------------------------------
__global__ __launch_bounds__(THREADS)
void count_kernel(const float* __restrict__ pred,
                  const float* __restrict__ tgt,
                  float* __restrict__ partial /* [BATCH][CHUNKS][NOUT] */)
{
    const int chunk = blockIdx.x;
    const int b     = blockIdx.y;
    const int tid   = threadIdx.x;

    __shared__ unsigned int cnt[3 * FBINS];     // 6 KB
    __shared__ float wtab[FBINS * NB];          // 32 KB
    __shared__ float pout[2][NOUT];

    #pragma unroll
    for (int k = 0; k < 3 * FBINS / THREADS; ++k)
        cnt[tid + k * THREADS] = 0u;

    // Gaussian weight table: wtab[f*16+i] = exp2(NEG_C2*(y_f - i)^2)
    #pragma unroll
    for (int k = 0; k < FBINS * NB / THREADS; ++k) {
        const int e = tid + k * THREADS;
        const int f = e >> 4;
        const int i = e & 15;
        const float y = ((float)f + 0.5f) * (15.0f / (float)FBINS);
        const float u = y - (float)i;
        wtab[e] = exp2_fast(u * u * NEG_C2);
    }
    __syncthreads();

    const float* pb = pred + (size_t)b * 3 * PLANE;
    const float* tb = tgt  + (size_t)b * 3 * PLANE;
    const int base = chunk * PX_PER_BLOCK + tid * 4;

    #pragma unroll
    for (int g = 0; g < GROUPS; ++g) {
        const int p = base + g * (THREADS * 4);
        const float4 P0 = *(const float4*)(pb + p);
        const float4 P1 = *(const float4*)(pb + PLANE + p);
        const float4 P2 = *(const float4*)(pb + 2 * PLANE + p);
        const float4 T0 = *(const float4*)(tb + p);
        const float4 T1 = *(const float4*)(tb + PLANE + p);
        const float4 T2 = *(const float4*)(tb + 2 * PLANE + p);

        const float p0a[4] = {P0.x, P0.y, P0.z, P0.w};
        const float p1a[4] = {P1.x, P1.y, P1.z, P1.w};
        const float p2a[4] = {P2.x, P2.y, P2.z, P2.w};
        const float t0a[4] = {T0.x, T0.y, T0.z, T0.w};
        const float t1a[4] = {T1.x, T1.y, T1.z, T1.w};
        const float t2a[4] = {T2.x, T2.y, T2.z, T2.w};

        #pragma unroll
        for (int j = 0; j < 4; ++j) {
            const bool m = (t0a[j] + t1a[j] + t2a[j]) * (1.0f / 3.0f) > 0.4f;
            if (m) {
                atomicAdd(&cnt[           qbin(p0a[j])], 1u);       // h=0 lo
                atomicAdd(&cnt[           qbin(p1a[j])], 65536u);   // h=1 hi
                atomicAdd(&cnt[FBINS    + qbin(p2a[j])], 1u);       // h=2 lo
                atomicAdd(&cnt[FBINS    + qbin(t0a[j])], 65536u);   // h=3 hi
                atomicAdd(&cnt[2*FBINS  + qbin(t1a[j])], 1u);       // h=4 lo
                atomicAdd(&cnt[2*FBINS  + qbin(t2a[j])], 65536u);   // h=5 hi
            }
        }
    }
    __syncthreads();

    // conv: threads 0..191: o = t%96 (ch=o/16, i=o&15), half = t/96 in {0,1}
    if (tid < 2 * NOUT) {
        const int o    = tid % NOUT;
        const int half = tid / NOUT;
        const int ch   = o >> 4;
        const int i    = o & 15;
        const int ch2  = ch >> 1;
        const int sh   = (ch & 1) * 16;

        float acc = 0.0f;
        const int f0 = half * (FBINS / 2);
        #pragma unroll 8
        for (int f = f0; f < f0 + FBINS / 2; ++f) {
            const float cf = (float)((cnt[ch2 * FBINS + f] >> sh) & 0xFFFFu);
            acc = fmaf(cf, wtab[(f << 4) + i], acc);
        }
        pout[half][o] = acc;
    }
    __syncthreads();

    if (tid < NOUT)
        partial[((size_t)b * CHUNKS + chunk) * NOUT + tid] =
            pout[0][tid] + pout[1][tid];
}

// ---------------------------------------------------------------------------
// 2) reduce partials over chunks, normalize, L1, mean.  One block, 768 thr.
// ---------------------------------------------------------------------------
__global__ __launch_bounds__(768)
void finalize_kernel(const float* __restrict__ partial,
                     float* __restrict__ out)
{
    const int t = threadIdx.x;          // 768 = BATCH * NOUT
    __shared__ float H[BATCH * NOUT];   // H[b*96 + ch*16 + i]

    {
        const int b = t / NOUT;
        const int o = t % NOUT;
        const float* base = partial + (size_t)b * CHUNKS * NOUT + o;
        float v = 0.0f;
        #pragma unroll 8
        for (int c = 0; c < CHUNKS; ++c)
            v += base[(size_t)c * NOUT];
        H[t] = v;
    }
    __syncthreads();

    // loss over 384 (b, c_pred, i) triples
    float val = 0.0f;
    if (t < 384) {
        const int b   = t / 48;
        const int rem = t % 48;
        const int c   = rem / NB;
        const int i   = rem % NB;

        const float* hp = H + b * NOUT + (c    ) * NB;  // pred ch c
        const float* ht = H + b * NOUT + (c + 3) * NB;  // target ch c
        float sp = 0.0f, st = 0.0f;
        #pragma unroll
        for (int k = 0; k < NB; ++k) { sp += hp[k]; st += ht[k]; }
        val = fabsf(hp[i] / (sp + 1e-7f) - ht[i] / (st + 1e-7f));
    }

    #pragma unroll
    for (int off = 32; off > 0; off >>= 1)
        val += __shfl_down(val, off, 64);

    __shared__ float r[12];
    const int lane = t & 63, wv = t >> 6;
    if (lane == 0) r[wv] = val;
    __syncthreads();
    if (t == 0) {
        float s = 0.0f;
        #pragma unroll
        for (int w = 0; w < 6; ++w) s += r[w];   // waves 6..11 saw t>=384
        out[0] = s * (1.0f / 384.0f);
    }
}

extern "C" void kernel_launch(void* const* d_in, const int* in_sizes, int n_in,
                              void* d_out, int out_size, void* d_ws, size_t ws_size,
                              hipStream_t stream)
{
    const float* pred = (const float*)d_in[0];
    const float* tgt  = (const float*)d_in[1];

    float* partial = (float*)d_ws;   // 8*128*96*4 = 393,216 bytes

    count_kernel<<<dim3(CHUNKS, BATCH), THREADS, 0, stream>>>(pred, tgt, partial);
    finalize_kernel<<<1, 768, 0, stream>>>(partial, (float*)d_out);
}

// Round 6
// 88.935 us; speedup vs baseline: 1.0557x; 1.0557x over previous
//
#include <hip/hip_runtime.h>

#define NB 16
#define BATCH 8
#define PLANE (512*512)           // 262144 px per channel plane
#define FBINS 512                 // fine histogram resolution
#define CHUNKS 128
#define CTHREADS 512              // count kernel: 8 waves/block
#define PX_PER_BLOCK (PLANE / CHUNKS)          // 2048 = CTHREADS*4
#define SLICES 8                               // fine-bin slices in combine
#define FPB (FBINS / SLICES)                   // 64 fine bins per combine block

#if __has_builtin(__builtin_amdgcn_exp2f)
__device__ __forceinline__ float exp2_fast(float x) { return __builtin_amdgcn_exp2f(x); }
#else
__device__ __forceinline__ float exp2_fast(float x) { return __expf(x * 0.69314718056f); }
#endif

// weight = exp(-128*(x - i/15)^2) = exp2( -(128*log2(e)/225) * (15x - i)^2 )
#define NEG_C2 (-0.8207331788f)

__device__ __forceinline__ int qbin(float x) {
    int f = (int)(x * (float)FBINS);
    return f > (FBINS - 1) ? (FBINS - 1) : f;
}

// ---------------------------------------------------------------------------
// 1) masked fine histogram. LDS: 3 arrays of FBINS u32, each word packs two
//    channels (lo16 = ch 2k, hi16 = ch 2k+1). Max count/half = 2048 -> no carry.
//    512 threads = 8 waves/block, 4 blocks/CU -> 32 waves/CU (100% occ).
//    Channel order h in [0,6): p0,p1,p2,t0,t1,t2.
// ---------------------------------------------------------------------------
__global__ __launch_bounds__(CTHREADS, 8)
void count_kernel(const float* __restrict__ pred,
                  const float* __restrict__ tgt,
                  unsigned int* __restrict__ partial
                  /* [3][BATCH][CHUNKS][FBINS] */)
{
    const int chunk = blockIdx.x;
    const int b     = blockIdx.y;
    const int tid   = threadIdx.x;

    __shared__ unsigned int cnt[3 * FBINS];   // 6 KB
    #pragma unroll
    for (int k = 0; k < 3 * FBINS / CTHREADS; ++k)
        cnt[tid + k * CTHREADS] = 0u;
    __syncthreads();

    const float* pb = pred + (size_t)b * 3 * PLANE;
    const float* tb = tgt  + (size_t)b * 3 * PLANE;
    const int p = chunk * PX_PER_BLOCK + tid * 4;

    const float4 P0 = *(const float4*)(pb + p);
    const float4 P1 = *(const float4*)(pb + PLANE + p);
    const float4 P2 = *(const float4*)(pb + 2 * PLANE + p);
    const float4 T0 = *(const float4*)(tb + p);
    const float4 T1 = *(const float4*)(tb + PLANE + p);
    const float4 T2 = *(const float4*)(tb + 2 * PLANE + p);

    const float p0a[4] = {P0.x, P0.y, P0.z, P0.w};
    const float p1a[4] = {P1.x, P1.y, P1.z, P1.w};
    const float p2a[4] = {P2.x, P2.y, P2.z, P2.w};
    const float t0a[4] = {T0.x, T0.y, T0.z, T0.w};
    const float t1a[4] = {T1.x, T1.y, T1.z, T1.w};
    const float t2a[4] = {T2.x, T2.y, T2.z, T2.w};

    #pragma unroll
    for (int j = 0; j < 4; ++j) {
        const bool m = (t0a[j] + t1a[j] + t2a[j]) * (1.0f / 3.0f) > 0.4f;
        if (m) {
            atomicAdd(&cnt[           qbin(p0a[j])], 1u);       // h=0 lo
            atomicAdd(&cnt[           qbin(p1a[j])], 65536u);   // h=1 hi
            atomicAdd(&cnt[FBINS    + qbin(p2a[j])], 1u);       // h=2 lo
            atomicAdd(&cnt[FBINS    + qbin(t0a[j])], 65536u);   // h=3 hi
            atomicAdd(&cnt[2*FBINS  + qbin(t1a[j])], 1u);       // h=4 lo
            atomicAdd(&cnt[2*FBINS  + qbin(t2a[j])], 65536u);   // h=5 hi
        }
    }
    __syncthreads();

    // flush 1536 words -> partial[h2][b][chunk][f]
    #pragma unroll
    for (int k = 0; k < 3 * FBINS / CTHREADS; ++k) {
        const int w  = tid + k * CTHREADS;
        const int h2 = w >> 9;
        const int f  = w & (FBINS - 1);
        partial[(((size_t)h2 * BATCH + b) * CHUNKS + chunk) * FBINS + f] = cnt[w];
    }
}

// ---------------------------------------------------------------------------
// 2) reduce partials over chunks + Gaussian conv -> out2[slice][hb][NB]
//    grid (SLICES, 48). Thread t: f_loc = t&63, quarter q = t>>6 sums 32 chunks.
// ---------------------------------------------------------------------------
__global__ __launch_bounds__(256)
void combine_kernel(const unsigned int* __restrict__ partial,
                    float* __restrict__ out2 /* [SLICES][48][NB] */)
{
    const int slice = blockIdx.x;
    const int hb    = blockIdx.y;      // h*BATCH + b
    const int h     = hb / BATCH;
    const int b     = hb % BATCH;
    const int h2    = h >> 1;
    const int sh    = (h & 1) * 16;
    const int tid   = threadIdx.x;

    const int f_loc = tid & (FPB - 1);
    const int q     = tid >> 6;        // 0..3, chunk quarter
    const int f     = slice * FPB + f_loc;

    const unsigned int* base =
        partial + (((size_t)h2 * BATCH + b) * CHUNKS + q * 32) * FBINS + f;
    unsigned int s = 0u;
    #pragma unroll 8
    for (int c = 0; c < 32; ++c)
        s += (base[(size_t)c * FBINS] >> sh) & 0xFFFFu;

    __shared__ unsigned int red[4][FPB];
    red[q][f_loc] = s;
    __syncthreads();

    if (tid < FPB) {   // wave 0 only
        const float cf = (float)(red[0][tid] + red[1][tid] + red[2][tid] + red[3][tid]);
        const float y  = ((float)(slice * FPB + tid) + 0.5f) * (15.0f / (float)FBINS);

        float acc[NB];
        #pragma unroll
        for (int i = 0; i < NB; ++i) {
            const float u = y - (float)i;
            acc[i] = cf * exp2_fast(u * u * NEG_C2);
        }
        #pragma unroll
        for (int off = 32; off > 0; off >>= 1)
            #pragma unroll
            for (int i = 0; i < NB; ++i)
                acc[i] += __shfl_down(acc[i], off, 64);

        if (tid == 0) {
            float* o = out2 + ((size_t)slice * 48 + hb) * NB;
            #pragma unroll
            for (int i = 0; i < NB; ++i) o[i] = acc[i];
        }
    }
}

// ---------------------------------------------------------------------------
// 3) sum slices, normalize, L1, mean
// ---------------------------------------------------------------------------
__global__ void finalize_kernel(const float* __restrict__ out2,
                                float* __restrict__ out)
{
    const int t = threadIdx.x;      // 384 threads
    __shared__ float H[48 * NB];    // [h*BATCH+b][i]

    for (int e = t; e < 48 * NB; e += 384) {
        float v = 0.0f;
        #pragma unroll
        for (int s = 0; s < SLICES; ++s)
            v += out2[(size_t)s * 48 * NB + e];
        H[e] = v;
    }
    __syncthreads();

    const int b   = t / 48;
    const int rem = t % 48;
    const int c   = rem / NB;
    const int i   = rem % NB;

    const float* hp = H + ((c    ) * BATCH + b) * NB;  // pred
    const float* ht = H + ((c + 3) * BATCH + b) * NB;  // target
    float sp = 0.0f, st = 0.0f;
    #pragma unroll
    for (int k = 0; k < NB; ++k) { sp += hp[k]; st += ht[k]; }

    float val = fabsf(hp[i] / (sp + 1e-7f) - ht[i] / (st + 1e-7f));

    #pragma unroll
    for (int off = 32; off > 0; off >>= 1)
        val += __shfl_down(val, off, 64);

    __shared__ float r[6];
    const int lane = t & 63, wv = t >> 6;
    if (lane == 0) r[wv] = val;
    __syncthreads();
    if (t == 0)
        out[0] = (r[0] + r[1] + r[2] + r[3] + r[4] + r[5]) * (1.0f / 384.0f);
}

extern "C" void kernel_launch(void* const* d_in, const int* in_sizes, int n_in,
                              void* d_out, int out_size, void* d_ws, size_t ws_size,
                              hipStream_t stream)
{
    const float* pred = (const float*)d_in[0];
    const float* tgt  = (const float*)d_in[1];

    unsigned int* partial = (unsigned int*)d_ws;  // 3*8*128*512*4 = 6.29 MB
    float* out2 = (float*)((char*)d_ws + (size_t)3 * BATCH * CHUNKS * FBINS * 4);

    count_kernel<<<dim3(CHUNKS, BATCH), CTHREADS, 0, stream>>>(pred, tgt, partial);
    combine_kernel<<<dim3(SLICES, 48), 256, 0, stream>>>(partial, out2);
    finalize_kernel<<<1, 384, 0, stream>>>(out2, (float*)d_out);
}